// Round 6
// baseline (338.534 us; speedup 1.0000x reference)
//
#include <hip/hip_runtime.h>
#include <hip/hip_bf16.h>
#include <stdint.h>

// Problem constants
#define B_   64
#define T_   300
#define NIN  2312
#define H1   512
#define H2   256
#define NOUT 101
#define KP   2368   // NIN padded up to a multiple of 64 (2368 = 37*64)
#define CH   15     // I1 staging chunk (timesteps); 300 = 20*15; 2*15*2KB = 60KB LDS

typedef __attribute__((ext_vector_type(8))) short bf16x8;
typedef __attribute__((ext_vector_type(4))) float f32x4;
typedef __attribute__((ext_vector_type(8))) unsigned short u16x8;

#define LDS_GLOAD16(g, l) \
  __builtin_amdgcn_global_load_lds((const __attribute__((address_space(1))) void*)(g), \
                                   (__attribute__((address_space(3))) void*)(l), 16, 0, 0)

// ---------------- transpose helper (tiny, perf-irrelevant) ----------------
__global__ void transpose_k(const float* __restrict__ src, float* __restrict__ dst,
                            int R, int C) {
    int idx = blockIdx.x * 256 + threadIdx.x;
    if (idx < R * C) {
        int r = idx / C, c = idx % C;
        dst[c * R + r] = src[r * C + c];
    }
}

// ---------------- fp32 -> bf16 (RNE) with K-padding, float4 loads ----------------
__device__ __forceinline__ unsigned short rne_bf16(float v) {
    union { float f; unsigned u; } cv; cv.f = v;
    return (unsigned short)((cv.u + 0x7fff + ((cv.u >> 16) & 1)) >> 16);
}

__global__ __launch_bounds__(256) void cvt_pad_bf16(const float* __restrict__ src,
                                                    unsigned short* __restrict__ dst,
                                                    int R, int C, int Cp) {
    int idx = blockIdx.x * 256 + threadIdx.x;
    int cpw = Cp >> 3;
    if (idx >= R * cpw) return;
    int row = idx / cpw;
    int c0 = (idx - row * cpw) << 3;
    u16x8 o;
    if (c0 + 8 <= C) {
        const float4* s = (const float4*)(src + (size_t)row * C + c0);
        float4 v0 = s[0], v1 = s[1];
        float v[8] = {v0.x, v0.y, v0.z, v0.w, v1.x, v1.y, v1.z, v1.w};
#pragma unroll
        for (int j = 0; j < 8; ++j) o[j] = rne_bf16(v[j]);
    } else {
#pragma unroll
        for (int j = 0; j < 8; ++j) {
            int k = c0 + j;
            o[j] = (k < C) ? rne_bf16(src[(size_t)row * C + k]) : (unsigned short)0;
        }
    }
    *(u16x8*)(dst + (size_t)row * Cp + c0) = o;
}

// ---------------- bf16 MFMA GEMM (m97 structure + XCD swizzle) ----------------
__global__ __launch_bounds__(256) void gemm_bf16(
    const unsigned short* __restrict__ Xb,   // [M][KP] bf16 bits
    const unsigned short* __restrict__ Wb,   // [H1][KP] bf16 bits
    float* __restrict__ Y)                   // [M][H1]
{
    __shared__ __align__(16) unsigned short As[128][64];
    __shared__ __align__(16) unsigned short Bs[128][64];

    const int tid  = threadIdx.x;
    const int wave = tid >> 6, lane = tid & 63;
    const int wr = wave >> 1, wc = wave & 1;          // 2x2 waves, 64x64 each

    // XCD-bijective swizzle: grid (4,150) = 600 blocks, 600 % 8 == 0.
    const int d  = blockIdx.x + gridDim.x * blockIdx.y;   // 0..599
    const int wg = (d & 7) * 75 + (d >> 3);
    const int bn = wg & 3, bm = wg >> 2;
    const int m0 = bm * 128, n0 = bn * 128;
    const int fr = lane & 15, fq = lane >> 4;

    f32x4 acc[4][4] = {};

    const size_t rowB = (size_t)KP * 2;
    const char* gA = (const char*)Xb + (size_t)(m0 + 32 * wave + (lane >> 3)) * rowB + (lane & 7) * 16;
    const char* gB = (const char*)Wb + (size_t)(n0 + 32 * wave + (lane >> 3)) * rowB + (lane & 7) * 16;
    unsigned short* lA = &As[32 * wave][0];
    unsigned short* lB = &Bs[32 * wave][0];

    for (int kt = 0; kt < KP / 64; ++kt) {
        const size_t ko = (size_t)kt * 128;           // byte offset along K
#pragma unroll
        for (int s = 0; s < 4; ++s) {
            LDS_GLOAD16(gA + ko + (size_t)s * 8 * rowB, lA + s * 8 * 64);
            LDS_GLOAD16(gB + ko + (size_t)s * 8 * rowB, lB + s * 8 * 64);
        }
        __syncthreads();
#pragma unroll
        for (int ks = 0; ks < 2; ++ks) {
            bf16x8 a[4], b[4];
#pragma unroll
            for (int mi = 0; mi < 4; ++mi)
                a[mi] = *(const bf16x8*)&As[wr * 64 + mi * 16 + fr][ks * 32 + fq * 8];
#pragma unroll
            for (int nj = 0; nj < 4; ++nj)
                b[nj] = *(const bf16x8*)&Bs[wc * 64 + nj * 16 + fr][ks * 32 + fq * 8];
#pragma unroll
            for (int mi = 0; mi < 4; ++mi)
#pragma unroll
                for (int nj = 0; nj < 4; ++nj)
                    acc[mi][nj] = __builtin_amdgcn_mfma_f32_16x16x32_bf16(
                        a[mi], b[nj], acc[mi][nj], 0, 0, 0);
        }
        __syncthreads();
    }

    // C/D layout (m89-verified): col = lane&15, row = (lane>>4)*4 + reg
#pragma unroll
    for (int mi = 0; mi < 4; ++mi)
#pragma unroll
        for (int nj = 0; nj < 4; ++nj) {
            int r0 = m0 + wr * 64 + mi * 16 + fq * 4;
            int c  = n0 + wc * 64 + nj * 16 + fr;
#pragma unroll
            for (int r = 0; r < 4; ++r)
                Y[(size_t)(r0 + r) * H1 + c] = acc[mi][nj][r];
        }
}

// ---------------- fp32 fallback GEMM (used only if ws too small) ----------------
#define GBM 128
#define GBN 128
#define GBK 16
__global__ __launch_bounds__(256) void gemm_ff(const float* __restrict__ X,
                                               const float* __restrict__ W,
                                               float* __restrict__ Y) {
    const int K = NIN, N = H1;
    __shared__ float As[GBK][GBM + 4];
    __shared__ float Bs[GBK][GBN + 4];
    const int bn = blockIdx.x, bm = blockIdx.y;
    const int tid = threadIdx.x;
    const int tx = tid & 15, ty = tid >> 4;
    const int m0 = bm * GBM, n0 = bn * GBN;
    float acc[8][8] = {};
    for (int k0 = 0; k0 < K; k0 += GBK) {
#pragma unroll
        for (int l = 0; l < 8; ++l) {
            int idx = l * 256 + tid;
            int kk = idx & 15, r = idx >> 4;
            int kg = k0 + kk;
            As[kk][r] = (kg < K) ? X[(size_t)(m0 + r) * K + kg] : 0.f;
        }
#pragma unroll
        for (int l = 0; l < 8; ++l) {
            int idx = l * 256 + tid;
            int kk = idx & 15, r = idx >> 4;
            int kg = k0 + kk;
            Bs[kk][r] = (kg < K) ? W[(size_t)(n0 + r) * K + kg] : 0.f;
        }
        __syncthreads();
#pragma unroll
        for (int kk = 0; kk < GBK; ++kk) {
            float a[8], b[8];
#pragma unroll
            for (int i = 0; i < 8; ++i) a[i] = As[kk][ty * 8 + i];
#pragma unroll
            for (int j = 0; j < 8; ++j) b[j] = Bs[kk][tx * 8 + j];
#pragma unroll
            for (int i = 0; i < 8; ++i)
#pragma unroll
                for (int j = 0; j < 8; ++j)
                    acc[i][j] = fmaf(a[i], b[j], acc[i][j]);
        }
        __syncthreads();
    }
#pragma unroll
    for (int i = 0; i < 8; ++i)
#pragma unroll
        for (int j = 0; j < 8; ++j)
            Y[(size_t)(m0 + ty * 8 + i) * N + n0 + tx * 8 + j] = acc[i][j];
}

// ---------------- wave-per-batch SNN scan (v5) ----------------
// One 64-lane wave per batch element, barrier-free.
// Lane owns L1 neurons 8*lane+j (j<8), L2 neurons 4*lane+j (j<4), outputs
// {lane, 64+lane}. Gathers are index-batched (all loads in flight together);
// the recurrent gather for step t+1 is issued at step t's ballot and
// accumulated after readout, hiding its latency under layer-2 compute.
__global__ __launch_bounds__(64) void snn_scan_wave(
    const float* __restrict__ I1ff,   // [B][T][H1]
    const float* __restrict__ wrt,    // [H1][H1]  wrt[i][h] = w_rec[h][i]
    const float* __restrict__ w2t,    // [H1][H2]  w2t[i][g] = w2[g][i]
    const float* __restrict__ w3t,    // [H2][NOUT] w3t[i][o] = w3[o][i]
    const float* __restrict__ alpha1, const float* __restrict__ rho1,
    const float* __restrict__ beta_a1,
    const float* __restrict__ alpha2, const float* __restrict__ rho2,
    const float* __restrict__ beta_a2,
    const float* __restrict__ beta_out,
    float* __restrict__ out)          // [B][NOUT]
{
    __shared__ __align__(16) float Ich[2][CH][H1];   // 60 KB

    const int b = blockIdx.x;
    const int lane = threadIdx.x;     // 0..63

    // ---- layer-1 state: neurons 8*lane+j ----
    float v1[8], a1[8], s1f[8], al1[8], oml1[8], rh1[8], ba1[8];
    {
        const float4* pa = (const float4*)(alpha1 + 8 * lane);
        const float4* pr = (const float4*)(rho1   + 8 * lane);
        const float4* pb = (const float4*)(beta_a1+ 8 * lane);
        float4 a0 = pa[0], a1v = pa[1], r0 = pr[0], r1 = pr[1], b0 = pb[0], b1 = pb[1];
        float av[8] = {a0.x,a0.y,a0.z,a0.w,a1v.x,a1v.y,a1v.z,a1v.w};
        float rv[8] = {r0.x,r0.y,r0.z,r0.w,r1.x,r1.y,r1.z,r1.w};
        float bv[8] = {b0.x,b0.y,b0.z,b0.w,b1.x,b1.y,b1.z,b1.w};
#pragma unroll
        for (int j = 0; j < 8; ++j) {
            v1[j] = 0.f; a1[j] = 0.f; s1f[j] = 0.f;
            al1[j] = av[j]; oml1[j] = 1.f - av[j]; rh1[j] = rv[j]; ba1[j] = bv[j];
        }
    }

    // ---- layer-2 state: neurons 4*lane+j ----
    float v2[4], a2[4], s2f[4], al2[4], oml2[4], rh2[4], ba2[4];
    {
        float4 a0 = *(const float4*)(alpha2 + 4 * lane);
        float4 r0 = *(const float4*)(rho2   + 4 * lane);
        float4 b0 = *(const float4*)(beta_a2+ 4 * lane);
        float av[4] = {a0.x,a0.y,a0.z,a0.w};
        float rv[4] = {r0.x,r0.y,r0.z,r0.w};
        float bv[4] = {b0.x,b0.y,b0.z,b0.w};
#pragma unroll
        for (int j = 0; j < 4; ++j) {
            v2[j] = 0.f; a2[j] = 0.f; s2f[j] = 0.f;
            al2[j] = av[j]; oml2[j] = 1.f - av[j]; rh2[j] = rv[j]; ba2[j] = bv[j];
        }
    }

    // ---- readout state ----
    float vo0 = 0.f, vo1 = 0.f, vs0 = 0.f, vs1 = 0.f;
    const float bo0 = beta_out[lane];
    const float ombo0 = 1.f - bo0;
    const float bo1 = (lane < NOUT - 64) ? beta_out[64 + lane] : 0.f;
    const float ombo1 = 1.f - bo1;

    // pipelined recurrent input for the CURRENT step (starts at 0: no spikes yet)
    float recp[8];
#pragma unroll
    for (int j = 0; j < 8; ++j) recp[j] = 0.f;

    const float* I1p = I1ff + (size_t)b * T_ * H1;

    // stage one chunk (CH rows of 512 floats): 2 x 1KB gload_lds per row
    auto stage = [&](int c, int buf) {
        const float* src = I1p + (size_t)c * CH * H1 + lane * 4;
#pragma unroll
        for (int s = 0; s < CH; ++s) {
            LDS_GLOAD16(src + (size_t)s * H1,       &Ich[buf][s][0]);
            LDS_GLOAD16(src + (size_t)s * H1 + 256, &Ich[buf][s][256]);
        }
    };

    stage(0, 0);

    for (int c = 0; c < T_ / CH; ++c) {
        const int buf = c & 1;
        asm volatile("s_waitcnt vmcnt(0)" ::: "memory");   // chunk c resident
        if (c + 1 < T_ / CH) stage(c + 1, buf ^ 1);

        for (int s = 0; s < CH; ++s) {
            // ---- I1 from LDS (lgkm path) ----
            const float4* cp = (const float4*)&Ich[buf][s][8 * lane];
            float4 c0 = cp[0], c1 = cp[1];
            float cur[8] = {c0.x,c0.y,c0.z,c0.w,c1.x,c1.y,c1.z,c1.w};

            // ---- layer-1 update (rec already prefetched in recp) ----
            unsigned long long S1[8];
#pragma unroll
            for (int j = 0; j < 8; ++j) {
                float I1  = cur[j] + recp[j];
                float v1n = al1[j] * v1[j] + oml1[j] * (I1 - a1[j]);
                bool  sp  = v1n > 1.f;
                v1[j] = sp ? v1n - 1.f : v1n;                 // soft reset
                a1[j] = rh1[j] * a1[j] + ba1[j] * s1f[j];     // uses PREVIOUS spike
                s1f[j] = sp ? 1.f : 0.f;
                S1[j] = __ballot(sp);
                recp[j] = 0.f;
            }

            // ---- collect spike indices (wave-uniform); batch up to 4 ----
            float I2[4] = {0.f, 0.f, 0.f, 0.f};
            int n = 0;
            int idx0 = 0, idx1 = 0, idx2 = 0, idx3 = 0;
#pragma unroll
            for (int j = 0; j < 8; ++j) {
                unsigned long long bits = S1[j];
                while (bits) {
                    int p = __builtin_ctzll(bits);
                    bits &= bits - 1;
                    int i = (p << 3) | j;                     // neuron id
                    if      (n == 0) idx0 = i;
                    else if (n == 1) idx1 = i;
                    else if (n == 2) idx2 = i;
                    else if (n == 3) idx3 = i;
                    else {
                        // overflow (rare): serial immediate accumulate
                        const float4* w2r = (const float4*)(w2t + (size_t)i * H2 + 4 * lane);
                        float4 q = *w2r;
                        I2[0] += q.x; I2[1] += q.y; I2[2] += q.z; I2[3] += q.w;
                        const float4* wr = (const float4*)(wrt + (size_t)i * H1 + 8 * lane);
                        float4 ra = wr[0], rb = wr[1];
                        recp[0] += ra.x; recp[1] += ra.y; recp[2] += ra.z; recp[3] += ra.w;
                        recp[4] += rb.x; recp[5] += rb.y; recp[6] += rb.z; recp[7] += rb.w;
                    }
                    ++n;
                }
            }

            // ---- batched loads: w2 rows first (needed first), then wrt rows ----
            float4 w2v0, w2v1, w2v2, w2v3;
            float4 wa0, wb0, wa1, wb1, wa2, wb2, wa3, wb3;
            if (n > 0) w2v0 = *(const float4*)(w2t + (size_t)idx0 * H2 + 4 * lane);
            if (n > 1) w2v1 = *(const float4*)(w2t + (size_t)idx1 * H2 + 4 * lane);
            if (n > 2) w2v2 = *(const float4*)(w2t + (size_t)idx2 * H2 + 4 * lane);
            if (n > 3) w2v3 = *(const float4*)(w2t + (size_t)idx3 * H2 + 4 * lane);
            if (n > 0) { const float4* r = (const float4*)(wrt + (size_t)idx0 * H1 + 8 * lane); wa0 = r[0]; wb0 = r[1]; }
            if (n > 1) { const float4* r = (const float4*)(wrt + (size_t)idx1 * H1 + 8 * lane); wa1 = r[0]; wb1 = r[1]; }
            if (n > 2) { const float4* r = (const float4*)(wrt + (size_t)idx2 * H1 + 8 * lane); wa2 = r[0]; wb2 = r[1]; }
            if (n > 3) { const float4* r = (const float4*)(wrt + (size_t)idx3 * H1 + 8 * lane); wa3 = r[0]; wb3 = r[1]; }

            if (n > 0) { I2[0] += w2v0.x; I2[1] += w2v0.y; I2[2] += w2v0.z; I2[3] += w2v0.w; }
            if (n > 1) { I2[0] += w2v1.x; I2[1] += w2v1.y; I2[2] += w2v1.z; I2[3] += w2v1.w; }
            if (n > 2) { I2[0] += w2v2.x; I2[1] += w2v2.y; I2[2] += w2v2.z; I2[3] += w2v2.w; }
            if (n > 3) { I2[0] += w2v3.x; I2[1] += w2v3.y; I2[2] += w2v3.z; I2[3] += w2v3.w; }

            // ---- layer-2 update ----
            unsigned long long S2[4];
#pragma unroll
            for (int j = 0; j < 4; ++j) {
                float v2n = al2[j] * v2[j] + oml2[j] * (I2[j] - a2[j]);
                bool  sp  = v2n > 1.f;
                v2[j] = sp ? v2n - 1.f : v2n;
                a2[j] = rh2[j] * a2[j] + ba2[j] * s2f[j];
                s2f[j] = sp ? 1.f : 0.f;
                S2[j] = __ballot(sp);
            }

            // ---- readout (layer-2 spikes are rare: fast skip) ----
            float io0 = 0.f, io1 = 0.f;
            if (S2[0] | S2[1] | S2[2] | S2[3]) {
#pragma unroll
                for (int j = 0; j < 4; ++j) {
                    unsigned long long bits = S2[j];
                    while (bits) {
                        int p = __builtin_ctzll(bits);
                        bits &= bits - 1;
                        int i = (p << 2) | j;
                        io0 += w3t[(size_t)i * NOUT + lane];
                        if (lane < NOUT - 64) io1 += w3t[(size_t)i * NOUT + 64 + lane];
                    }
                }
            }
            vo0 = bo0 * vo0 + ombo0 * io0;
            vo1 = bo1 * vo1 + ombo1 * io1;
            vs0 += vo0;
            vs1 += vo1;

            // ---- accumulate prefetched recurrent rows for NEXT step ----
            if (n > 0) { recp[0]+=wa0.x; recp[1]+=wa0.y; recp[2]+=wa0.z; recp[3]+=wa0.w;
                         recp[4]+=wb0.x; recp[5]+=wb0.y; recp[6]+=wb0.z; recp[7]+=wb0.w; }
            if (n > 1) { recp[0]+=wa1.x; recp[1]+=wa1.y; recp[2]+=wa1.z; recp[3]+=wa1.w;
                         recp[4]+=wb1.x; recp[5]+=wb1.y; recp[6]+=wb1.z; recp[7]+=wb1.w; }
            if (n > 2) { recp[0]+=wa2.x; recp[1]+=wa2.y; recp[2]+=wa2.z; recp[3]+=wa2.w;
                         recp[4]+=wb2.x; recp[5]+=wb2.y; recp[6]+=wb2.z; recp[7]+=wb2.w; }
            if (n > 3) { recp[0]+=wa3.x; recp[1]+=wa3.y; recp[2]+=wa3.z; recp[3]+=wa3.w;
                         recp[4]+=wb3.x; recp[5]+=wb3.y; recp[6]+=wb3.z; recp[7]+=wb3.w; }
        }
    }

    out[b * NOUT + lane] = vs0 * (1.f / (float)T_);
    if (lane < NOUT - 64) out[b * NOUT + 64 + lane] = vs1 * (1.f / (float)T_);
}

// ---------------- launch ----------------
extern "C" void kernel_launch(void* const* d_in, const int* in_sizes, int n_in,
                              void* d_out, int out_size, void* d_ws, size_t ws_size,
                              hipStream_t stream) {
    const float* x      = (const float*)d_in[0];   // [B][T][NIN]
    const float* w1     = (const float*)d_in[1];   // [H1][NIN]
    const float* w_rec  = (const float*)d_in[2];   // [H1][H1]
    const float* w2     = (const float*)d_in[3];   // [H2][H1]
    const float* w3     = (const float*)d_in[4];   // [NOUT][H2]
    const float* alpha1 = (const float*)d_in[5];
    const float* rho1   = (const float*)d_in[6];
    const float* beta_a1= (const float*)d_in[7];
    const float* alpha2 = (const float*)d_in[8];
    const float* rho2   = (const float*)d_in[9];
    const float* beta_a2= (const float*)d_in[10];
    const float* beta_out=(const float*)d_in[11];
    float* out = (float*)d_out;

    const int M = B_ * T_;                         // 19200

    size_t off = 0;
    auto take = [&](size_t bytes) {
        void* p = (char*)d_ws + off;
        off += (bytes + 255) & ~(size_t)255;
        return p;
    };
    float* I1ff = (float*)take((size_t)M * H1 * 4);            // 39.3 MB
    float* wrt  = (float*)take((size_t)H1 * H1 * 4);
    float* w2t  = (float*)take((size_t)H1 * H2 * 4);
    float* w3t  = (float*)take((size_t)H2 * NOUT * 4);
    unsigned short* xb  = (unsigned short*)take((size_t)M * KP * 2);   // 90.9 MB
    unsigned short* w1b = (unsigned short*)take((size_t)H1 * KP * 2);  // 2.4 MB
    bool use_bf16 = (off <= ws_size);

    transpose_k<<<(H1 * H1 + 255) / 256, 256, 0, stream>>>(w_rec, wrt, H1, H1);
    transpose_k<<<(H2 * H1 + 255) / 256, 256, 0, stream>>>(w2, w2t, H2, H1);
    transpose_k<<<(NOUT * H2 + 255) / 256, 256, 0, stream>>>(w3, w3t, NOUT, H2);

    if (use_bf16) {
        int nx = M * (KP / 8);
        cvt_pad_bf16<<<(nx + 255) / 256, 256, 0, stream>>>(x, xb, M, NIN, KP);
        int nw = H1 * (KP / 8);
        cvt_pad_bf16<<<(nw + 255) / 256, 256, 0, stream>>>(w1, w1b, H1, NIN, KP);

        dim3 gg(H1 / 128, M / 128);   // (4, 150) = 600 blocks (swizzle assumes 600)
        gemm_bf16<<<gg, 256, 0, stream>>>(xb, w1b, I1ff);
    } else {
        dim3 gg(H1 / GBN, M / GBM);
        gemm_ff<<<gg, 256, 0, stream>>>(x, w1, I1ff);
    }

    snn_scan_wave<<<B_, 64, 0, stream>>>(I1ff, wrt, w2t, w3t,
                                         alpha1, rho1, beta_a1,
                                         alpha2, rho2, beta_a2,
                                         beta_out, out);
}

// Round 7
// 229.414 us; speedup vs baseline: 1.4756x; 1.4756x over previous
//
#include <hip/hip_runtime.h>
#include <hip/hip_bf16.h>
#include <stdint.h>

// Problem constants
#define B_   64
#define T_   300
#define NIN  2312
#define H1   512
#define H2   256
#define NOUT 101
#define KP   2368   // NIN padded to multiple of 64
#define CH   15     // I1 staging chunk (timesteps); 300 = 20*15
#define NC   (T_ / CH)

typedef __attribute__((ext_vector_type(8))) short bf16x8;
typedef __attribute__((ext_vector_type(4))) float f32x4;
typedef __attribute__((ext_vector_type(8))) unsigned short u16x8;

#define LDS_GLOAD16(g, l) \
  __builtin_amdgcn_global_load_lds((const __attribute__((address_space(1))) void*)(g), \
                                   (__attribute__((address_space(3))) void*)(l), 16, 0, 0)

// ---------------- transpose helper ----------------
__global__ void transpose_k(const float* __restrict__ src, float* __restrict__ dst,
                            int R, int C) {
    int idx = blockIdx.x * 256 + threadIdx.x;
    if (idx < R * C) {
        int r = idx / C, c = idx % C;
        dst[c * R + r] = src[r * C + c];
    }
}

// ---------------- fp32 -> bf16 (RNE) with K-padding (W only now) ----------------
__device__ __forceinline__ unsigned short rne_bf16(float v) {
    union { float f; unsigned u; } cv; cv.f = v;
    return (unsigned short)((cv.u + 0x7fff + ((cv.u >> 16) & 1)) >> 16);
}

__global__ __launch_bounds__(256) void cvt_pad_bf16(const float* __restrict__ src,
                                                    unsigned short* __restrict__ dst,
                                                    int R, int C, int Cp) {
    int idx = blockIdx.x * 256 + threadIdx.x;
    int cpw = Cp >> 3;
    if (idx >= R * cpw) return;
    int row = idx / cpw;
    int c0 = (idx - row * cpw) << 3;
    u16x8 o;
#pragma unroll
    for (int j = 0; j < 8; ++j) {
        int k = c0 + j;
        o[j] = (k < C) ? rne_bf16(src[(size_t)row * C + k]) : (unsigned short)0;
    }
    *(u16x8*)(dst + (size_t)row * Cp + c0) = o;
}

// ---------------- bf16 MFMA GEMM, fused A-side fp32->bf16 conversion ----------
// Y[M][H1] = bf16(X[M][NIN]) * Wb[H1][KP]^T.  A: fp32 global -> reg -> cvt ->
// ds_write_b128.  B: pre-converted bf16 via global_load_lds.  XCD swizzle.
__device__ __forceinline__ unsigned pack2bf(float lo, float hi) {
    return ((unsigned)rne_bf16(hi) << 16) | rne_bf16(lo);
}

__global__ __launch_bounds__(256) void gemm_bf16_fa(
    const float* __restrict__ X,             // [M][NIN] fp32
    const unsigned short* __restrict__ Wb,   // [H1][KP] bf16 bits
    float* __restrict__ Y)                   // [M][H1]
{
    __shared__ __align__(16) unsigned short As[128][64];
    __shared__ __align__(16) unsigned short Bs[128][64];

    const int tid  = threadIdx.x;
    const int wave = tid >> 6, lane = tid & 63;
    const int wr = wave >> 1, wc = wave & 1;          // 2x2 waves, 64x64 each

    // XCD-bijective swizzle: 600 blocks, 600 % 8 == 0.
    const int d  = blockIdx.x + gridDim.x * blockIdx.y;   // 0..599
    const int wg = (d & 7) * 75 + (d >> 3);
    const int bn = wg & 3, bm = wg >> 2;
    const int m0 = bm * 128, n0 = bn * 128;
    const int fr = lane & 15, fq = lane >> 4;

    f32x4 acc[4][4] = {};

    // A addressing (fp32 source): row = m0 + 32w + s*8 + (lane>>3), cols acol..acol+8
    const int arl  = lane >> 3;          // 0..7
    const int acol = 8 * (lane & 7);     // 0..56
    const float* gAf = X + (size_t)(m0 + 32 * wave + arl) * NIN + acol;
    unsigned short* lAa = &As[32 * wave + arl][acol];

    // B addressing (bf16 source, wave-uniform LDS dest)
    const size_t rowBW = (size_t)KP * 2;
    const char* gB = (const char*)Wb + (size_t)(n0 + 32 * wave + (lane >> 3)) * rowBW + (lane & 7) * 16;
    unsigned short* lB = &Bs[32 * wave][0];

    for (int kt = 0; kt < KP / 64; ++kt) {
        const int kc = kt * 64;
        // ---- A: 8 x float4 fp32 loads (issued first) ----
        float4 fa[4], fb[4];
#pragma unroll
        for (int s = 0; s < 4; ++s) {
            if (kc + acol < NIN) {   // NIN%8==0: vector fully valid or fully pad
                const float4* p = (const float4*)(gAf + (size_t)s * 8 * NIN + kc);
                fa[s] = p[0]; fb[s] = p[1];
            } else {
                fa[s] = make_float4(0.f, 0.f, 0.f, 0.f);
                fb[s] = make_float4(0.f, 0.f, 0.f, 0.f);
            }
        }
        // ---- B: async global->LDS ----
        const size_t ko = (size_t)kt * 128;
#pragma unroll
        for (int s = 0; s < 4; ++s)
            LDS_GLOAD16(gB + ko + (size_t)s * 8 * rowBW, lB + s * 8 * 64);
        // ---- A: cvt + LDS write ----
#pragma unroll
        for (int s = 0; s < 4; ++s) {
            uint4 o;
            o.x = pack2bf(fa[s].x, fa[s].y);
            o.y = pack2bf(fa[s].z, fa[s].w);
            o.z = pack2bf(fb[s].x, fb[s].y);
            o.w = pack2bf(fb[s].z, fb[s].w);
            *(uint4*)(lAa + (size_t)s * 8 * 64) = o;
        }
        __syncthreads();
#pragma unroll
        for (int ks = 0; ks < 2; ++ks) {
            bf16x8 a[4], b[4];
#pragma unroll
            for (int mi = 0; mi < 4; ++mi)
                a[mi] = *(const bf16x8*)&As[wr * 64 + mi * 16 + fr][ks * 32 + fq * 8];
#pragma unroll
            for (int nj = 0; nj < 4; ++nj)
                b[nj] = *(const bf16x8*)&Bs[wc * 64 + nj * 16 + fr][ks * 32 + fq * 8];
#pragma unroll
            for (int mi = 0; mi < 4; ++mi)
#pragma unroll
                for (int nj = 0; nj < 4; ++nj)
                    acc[mi][nj] = __builtin_amdgcn_mfma_f32_16x16x32_bf16(
                        a[mi], b[nj], acc[mi][nj], 0, 0, 0);
        }
        __syncthreads();
    }

    // C/D layout (m89-verified): col = lane&15, row = (lane>>4)*4 + reg
#pragma unroll
    for (int mi = 0; mi < 4; ++mi)
#pragma unroll
        for (int nj = 0; nj < 4; ++nj) {
            int r0 = m0 + wr * 64 + mi * 16 + fq * 4;
            int c  = n0 + wc * 64 + nj * 16 + fr;
#pragma unroll
            for (int r = 0; r < 4; ++r)
                Y[(size_t)(r0 + r) * H1 + c] = acc[mi][nj][r];
        }
}

// ---------------- wave-per-batch SNN scan (v6) ----------------
// One 64-lane wave per batch element, barrier-free. h = lane + 64j mapping.
// Fast paths: ONE ballot per layer detects "no spikes anywhere" (the common
// case) and skips mask building + gathers entirely. cur is ds_read-prefetched
// one step ahead. Chunk staging is issued at chunk END so rare-path gather
// waits never drain the staging FIFO (vmcnt is oldest-first).
__global__ __launch_bounds__(64) void snn_scan_wave(
    const float* __restrict__ I1ff,   // [B][T][H1]
    const float* __restrict__ wrt,    // [H1][H1]  wrt[i][h] = w_rec[h][i]
    const float* __restrict__ w2t,    // [H1][H2]  w2t[i][g] = w2[g][i]
    const float* __restrict__ w3t,    // [H2][NOUT] w3t[i][o] = w3[o][i]
    const float* __restrict__ alpha1, const float* __restrict__ rho1,
    const float* __restrict__ beta_a1,
    const float* __restrict__ alpha2, const float* __restrict__ rho2,
    const float* __restrict__ beta_a2,
    const float* __restrict__ beta_out,
    float* __restrict__ out)          // [B][NOUT]
{
    __shared__ __align__(16) float Ich[2][CH][H1];   // 60 KB

    const int b = blockIdx.x;
    const int lane = threadIdx.x;     // 0..63

    // layer-1 state: neurons h = lane + 64j, j<8
    float v1[8], a1[8], s1f[8], al1[8], oml1[8], rh1[8], ba1[8];
#pragma unroll
    for (int j = 0; j < 8; ++j) {
        int h = lane + 64 * j;
        v1[j] = 0.f; a1[j] = 0.f; s1f[j] = 0.f;
        al1[j] = alpha1[h]; oml1[j] = 1.f - al1[j];
        rh1[j] = rho1[h];   ba1[j] = beta_a1[h];
    }
    // layer-2 state: neurons h = lane + 64j, j<4
    float v2[4], a2[4], s2f[4], al2[4], oml2[4], rh2[4], ba2[4];
#pragma unroll
    for (int j = 0; j < 4; ++j) {
        int h = lane + 64 * j;
        v2[j] = 0.f; a2[j] = 0.f; s2f[j] = 0.f;
        al2[j] = alpha2[h]; oml2[j] = 1.f - al2[j];
        rh2[j] = rho2[h];   ba2[j] = beta_a2[h];
    }
    // readout
    float vo0 = 0.f, vo1 = 0.f, vs0 = 0.f, vs1 = 0.f;
    const float bo0 = beta_out[lane];
    const float ombo0 = 1.f - bo0;
    const float bo1 = (lane < NOUT - 64) ? beta_out[64 + lane] : 0.f;
    const float ombo1 = 1.f - bo1;

    unsigned long long M1[8];
#pragma unroll
    for (int j = 0; j < 8; ++j) M1[j] = 0ull;
    bool prev1 = false;   // any layer-1 spike last step?

    const float* I1p = I1ff + (size_t)b * T_ * H1;

    auto stage = [&](int c, int bufi) {
        const float* src = I1p + (size_t)c * CH * H1 + lane * 4;
#pragma unroll
        for (int s = 0; s < CH; ++s) {
            LDS_GLOAD16(src + (size_t)s * H1,       &Ich[bufi][s][0]);
            LDS_GLOAD16(src + (size_t)s * H1 + 256, &Ich[bufi][s][256]);
        }
    };

    stage(0, 0);

    for (int c = 0; c < NC; ++c) {
        const int buf = c & 1;
        asm volatile("s_waitcnt vmcnt(0)" ::: "memory");   // chunk c resident

        // cur for s=0 (exposed ds_read once per chunk)
        float cur[8];
#pragma unroll
        for (int j = 0; j < 8; ++j) cur[j] = Ich[buf][0][lane + 64 * j];

        for (int s = 0; s < CH; ++s) {
            // prefetch next step's I1 (latency hides under this step's body)
            float nxt[8];
            if (s + 1 < CH) {
#pragma unroll
                for (int j = 0; j < 8; ++j) nxt[j] = Ich[buf][s + 1][lane + 64 * j];
            }

            // ---- recurrent input (rare path; uses PREVIOUS step's masks) ----
            float rec[8] = {0.f,0.f,0.f,0.f,0.f,0.f,0.f,0.f};
            if (prev1) {
#pragma unroll
                for (int w = 0; w < 8; ++w) {
                    unsigned long long bits = M1[w];
                    while (bits) {
                        int p = __builtin_ctzll(bits);
                        bits &= bits - 1;
                        int i = (w << 6) + p;
                        const float* r = wrt + (size_t)i * H1 + lane;
#pragma unroll
                        for (int j = 0; j < 8; ++j) rec[j] += r[64 * j];
                    }
                }
            }

            // ---- layer-1 update ----
            unsigned m = 0;
#pragma unroll
            for (int j = 0; j < 8; ++j) {
                float I1v = cur[j] + rec[j];
                float v1n = fmaf(al1[j], v1[j], oml1[j] * (I1v - a1[j]));
                bool  sp  = v1n > 1.f;
                v1[j] = sp ? v1n - 1.f : v1n;                  // soft reset
                a1[j] = fmaf(rh1[j], a1[j], ba1[j] * s1f[j]);  // prev spike
                s1f[j] = sp ? 1.f : 0.f;
                m |= (sp ? 1u : 0u) << j;
            }

            unsigned long long anyb = __ballot(m != 0);
            float I2[4] = {0.f, 0.f, 0.f, 0.f};
            if (anyb) {                       // rare: build masks + gather w2
                prev1 = true;
#pragma unroll
                for (int j = 0; j < 8; ++j) M1[j] = __ballot((m >> j) & 1);
#pragma unroll
                for (int w = 0; w < 8; ++w) {
                    unsigned long long bits = M1[w];
                    while (bits) {
                        int p = __builtin_ctzll(bits);
                        bits &= bits - 1;
                        int i = (w << 6) + p;
                        const float* r = w2t + (size_t)i * H2 + lane;
#pragma unroll
                        for (int j = 0; j < 4; ++j) I2[j] += r[64 * j];
                    }
                }
            } else {
                prev1 = false;
            }

            // ---- layer-2 update ----
            unsigned m2 = 0;
#pragma unroll
            for (int j = 0; j < 4; ++j) {
                float v2n = fmaf(al2[j], v2[j], oml2[j] * (I2[j] - a2[j]));
                bool  sp  = v2n > 1.f;
                v2[j] = sp ? v2n - 1.f : v2n;
                a2[j] = fmaf(rh2[j], a2[j], ba2[j] * s2f[j]);
                s2f[j] = sp ? 1.f : 0.f;
                m2 |= (sp ? 1u : 0u) << j;
            }

            unsigned long long any2 = __ballot(m2 != 0);
            float io0 = 0.f, io1 = 0.f;
            if (any2) {                       // very rare
#pragma unroll
                for (int w = 0; w < 4; ++w) {
                    unsigned long long bits = __ballot((m2 >> w) & 1);
                    while (bits) {
                        int p = __builtin_ctzll(bits);
                        bits &= bits - 1;
                        int i = (w << 6) + p;
                        io0 += w3t[(size_t)i * NOUT + lane];
                        if (lane < NOUT - 64) io1 += w3t[(size_t)i * NOUT + 64 + lane];
                    }
                }
            }
            vo0 = fmaf(bo0, vo0, ombo0 * io0);
            vo1 = fmaf(bo1, vo1, ombo1 * io1);
            vs0 += vo0;
            vs1 += vo1;

#pragma unroll
            for (int j = 0; j < 8; ++j) cur[j] = nxt[j];
        }

        // issue next chunk's staging AFTER all of this chunk's gathers:
        // rare-path waits never drain these; latency exposed only at the
        // next chunk-top waitcnt (~1 HBM latency per 15 steps).
        if (c + 1 < NC) stage(c + 1, buf ^ 1);
    }

    out[b * NOUT + lane] = vs0 * (1.f / (float)T_);
    if (lane < NOUT - 64) out[b * NOUT + 64 + lane] = vs1 * (1.f / (float)T_);
}

// ---------------- launch ----------------
extern "C" void kernel_launch(void* const* d_in, const int* in_sizes, int n_in,
                              void* d_out, int out_size, void* d_ws, size_t ws_size,
                              hipStream_t stream) {
    const float* x      = (const float*)d_in[0];   // [B][T][NIN]
    const float* w1     = (const float*)d_in[1];   // [H1][NIN]
    const float* w_rec  = (const float*)d_in[2];   // [H1][H1]
    const float* w2     = (const float*)d_in[3];   // [H2][H1]
    const float* w3     = (const float*)d_in[4];   // [NOUT][H2]
    const float* alpha1 = (const float*)d_in[5];
    const float* rho1   = (const float*)d_in[6];
    const float* beta_a1= (const float*)d_in[7];
    const float* alpha2 = (const float*)d_in[8];
    const float* rho2   = (const float*)d_in[9];
    const float* beta_a2= (const float*)d_in[10];
    const float* beta_out=(const float*)d_in[11];
    float* out = (float*)d_out;

    const int M = B_ * T_;                         // 19200

    size_t off = 0;
    auto take = [&](size_t bytes) {
        void* p = (char*)d_ws + off;
        off += (bytes + 255) & ~(size_t)255;
        return p;
    };
    float* I1ff = (float*)take((size_t)M * H1 * 4);            // 39.3 MB
    float* wrt  = (float*)take((size_t)H1 * H1 * 4);
    float* w2t  = (float*)take((size_t)H1 * H2 * 4);
    float* w3t  = (float*)take((size_t)H2 * NOUT * 4);
    unsigned short* w1b = (unsigned short*)take((size_t)H1 * KP * 2);  // 2.4 MB

    transpose_k<<<(H1 * H1 + 255) / 256, 256, 0, stream>>>(w_rec, wrt, H1, H1);
    transpose_k<<<(H2 * H1 + 255) / 256, 256, 0, stream>>>(w2, w2t, H2, H1);
    transpose_k<<<(NOUT * H2 + 255) / 256, 256, 0, stream>>>(w3, w3t, NOUT, H2);

    // W -> bf16 (tiny); A converts in-GEMM
    int nw = H1 * (KP / 8);
    cvt_pad_bf16<<<(nw + 255) / 256, 256, 0, stream>>>(w1, w1b, H1, NIN, KP);

    dim3 gg(H1 / 128, M / 128);   // (4, 150) = 600 blocks (swizzle assumes 600)
    gemm_bf16_fa<<<gg, 256, 0, stream>>>(x, w1b, I1ff);

    snn_scan_wave<<<B_, 64, 0, stream>>>(I1ff, wrt, w2t, w3t,
                                         alpha1, rho1, beta_a1,
                                         alpha2, rho2, beta_a2,
                                         beta_out, out);
}

// Round 8
// 220.699 us; speedup vs baseline: 1.5339x; 1.0395x over previous
//
#include <hip/hip_runtime.h>
#include <hip/hip_bf16.h>
#include <stdint.h>

// Problem constants
#define B_   64
#define T_   300
#define NIN  2312
#define H1   512
#define H2   256
#define NOUT 101
#define KP   2368   // NIN padded to multiple of 64
#define NT   (KP / 64)
#define CH   15     // I1 staging chunk (timesteps); 300 = 20*15
#define NC   (T_ / CH)

typedef __attribute__((ext_vector_type(8))) short bf16x8;
typedef __attribute__((ext_vector_type(4))) float f32x4;
typedef __attribute__((ext_vector_type(8))) unsigned short u16x8;

#define LDS_GLOAD16(g, l) \
  __builtin_amdgcn_global_load_lds((const __attribute__((address_space(1))) void*)(g), \
                                   (__attribute__((address_space(3))) void*)(l), 16, 0, 0)
#define CFENCE() asm volatile("" ::: "memory")

// ---------------- transpose helper ----------------
__global__ void transpose_k(const float* __restrict__ src, float* __restrict__ dst,
                            int R, int C) {
    int idx = blockIdx.x * 256 + threadIdx.x;
    if (idx < R * C) {
        int r = idx / C, c = idx % C;
        dst[c * R + r] = src[r * C + c];
    }
}

// ---------------- fp32 -> bf16 (RNE) with K-padding (W only) ----------------
__device__ __forceinline__ unsigned short rne_bf16(float v) {
    union { float f; unsigned u; } cv; cv.f = v;
    return (unsigned short)((cv.u + 0x7fff + ((cv.u >> 16) & 1)) >> 16);
}

__global__ __launch_bounds__(256) void cvt_pad_bf16(const float* __restrict__ src,
                                                    unsigned short* __restrict__ dst,
                                                    int R, int C, int Cp) {
    int idx = blockIdx.x * 256 + threadIdx.x;
    int cpw = Cp >> 3;
    if (idx >= R * cpw) return;
    int row = idx / cpw;
    int c0 = (idx - row * cpw) << 3;
    u16x8 o;
#pragma unroll
    for (int j = 0; j < 8; ++j) {
        int k = c0 + j;
        o[j] = (k < C) ? rne_bf16(src[(size_t)row * C + k]) : (unsigned short)0;
    }
    *(u16x8*)(dst + (size_t)row * Cp + c0) = o;
}

// ---------------- bf16 MFMA GEMM: fused A-cvt, XOR-swizzled LDS, counted vmcnt --
// Y[M][H1] = bf16(X[M][NIN]) * Wb[H1][KP]^T
// LDS swizzle: LDS[row][cb] holds global[row][cb ^ 16*(row&7)] (bytes) for both
// A (swizzled ds_write dest) and B (pre-swizzled per-lane gload source).
// Reads use col ^ ((row&7)<<3) elements -> 2-way conflicts only (free).
__device__ __forceinline__ unsigned pack2bf(float lo, float hi) {
    return ((unsigned)rne_bf16(hi) << 16) | rne_bf16(lo);
}

__global__ __launch_bounds__(256) void gemm_bf16_fa(
    const float* __restrict__ X,             // [M][NIN] fp32
    const unsigned short* __restrict__ Wb,   // [H1][KP] bf16 bits
    float* __restrict__ Y)                   // [M][H1]
{
    __shared__ __align__(16) unsigned short As[128][64];
    __shared__ __align__(16) unsigned short Bs[128][64];

    const int tid  = threadIdx.x;
    const int wave = tid >> 6, lane = tid & 63;
    const int wr = wave >> 1, wc = wave & 1;          // 2x2 waves, 64x64 each

    // XCD-bijective swizzle: 600 blocks, 600 % 8 == 0.
    const int d  = blockIdx.x + gridDim.x * blockIdx.y;   // 0..599
    const int wg = (d & 7) * 75 + (d >> 3);
    const int bn = wg & 3, bm = wg >> 2;
    const int m0 = bm * 128, n0 = bn * 128;
    const int fr = lane & 15, fq = lane >> 4;
    const int swz = (fr & 7) << 3;                    // element XOR for reads

    f32x4 acc[4][4] = {};

    // ---- A addressing (fp32 source; reg-staged; swizzled ds_write dest) ----
    const int arl  = lane >> 3;                       // row-sub 0..7
    const int acol = 8 * (lane & 7);                  // source col (elements)
    const float* gAf = X + (size_t)(m0 + 32 * wave + arl) * NIN + acol;
    // dest col swizzled: 8*((lane&7) ^ (arl&7))
    unsigned short* lAa = &As[32 * wave + arl][8 * ((lane & 7) ^ (arl & 7))];

    // ---- B addressing (bf16 source; pre-swizzled per-lane source col) ----
    const size_t rowBW = (size_t)KP * 2;
    const int bcolsw = 16 * ((lane & 7) ^ ((lane >> 3) & 7));   // bytes
    const char* gB = (const char*)Wb + (size_t)(n0 + 32 * wave + (lane >> 3)) * rowBW + bcolsw;
    unsigned short* lB = &Bs[32 * wave][0];

    // prologue: load A(0)
    float4 fa[4], fb[4];
#pragma unroll
    for (int s = 0; s < 4; ++s) {
        const float4* p = (const float4*)(gAf + (size_t)s * 8 * NIN);
        fa[s] = p[0]; fb[s] = p[1];
    }

    for (int kt = 0; kt < NT; ++kt) {
        // ---- B async stage ----
        const size_t ko = (size_t)kt * 128;
        CFENCE();
#pragma unroll
        for (int s = 0; s < 4; ++s)
            LDS_GLOAD16(gB + ko + (size_t)s * 8 * rowBW, lB + s * 8 * 64);
        CFENCE();
        // ---- A: cvt + swizzled LDS write (compiler waits A regs, vmcnt(4)) ----
#pragma unroll
        for (int s = 0; s < 4; ++s) {
            uint4 o;
            o.x = pack2bf(fa[s].x, fa[s].y);
            o.y = pack2bf(fa[s].z, fa[s].w);
            o.z = pack2bf(fb[s].x, fb[s].y);
            o.w = pack2bf(fb[s].z, fb[s].w);
            *(uint4*)(lAa + (size_t)s * 8 * 64) = o;
        }
        CFENCE();
        // ---- prefetch A(kt+1): stays in flight across MFMA (vmcnt(8)) ----
        if (kt + 1 < NT) {
            const int kc = (kt + 1) * 64;
#pragma unroll
            for (int s = 0; s < 4; ++s) {
                if (kc + acol < NIN) {   // NIN%8==0: float4 pair fully valid or pad
                    const float4* p = (const float4*)(gAf + (size_t)s * 8 * NIN + kc);
                    fa[s] = p[0]; fb[s] = p[1];
                } else {
                    fa[s] = make_float4(0.f, 0.f, 0.f, 0.f);
                    fb[s] = make_float4(0.f, 0.f, 0.f, 0.f);
                }
            }
            CFENCE();
            asm volatile("s_waitcnt vmcnt(8)" ::: "memory");   // B landed; A in flight
        } else {
            CFENCE();
            asm volatile("s_waitcnt vmcnt(0)" ::: "memory");
        }
        asm volatile("s_waitcnt lgkmcnt(0)" ::: "memory");     // ds_writes visible
        __builtin_amdgcn_s_barrier();

#pragma unroll
        for (int ks = 0; ks < 2; ++ks) {
            bf16x8 a[4], b[4];
#pragma unroll
            for (int mi = 0; mi < 4; ++mi)
                a[mi] = *(const bf16x8*)&As[wr * 64 + mi * 16 + fr][(ks * 32 + fq * 8) ^ swz];
#pragma unroll
            for (int nj = 0; nj < 4; ++nj)
                b[nj] = *(const bf16x8*)&Bs[wc * 64 + nj * 16 + fr][(ks * 32 + fq * 8) ^ swz];
#pragma unroll
            for (int mi = 0; mi < 4; ++mi)
#pragma unroll
                for (int nj = 0; nj < 4; ++nj)
                    acc[mi][nj] = __builtin_amdgcn_mfma_f32_16x16x32_bf16(
                        a[mi], b[nj], acc[mi][nj], 0, 0, 0);
        }
        __builtin_amdgcn_s_barrier();   // all waves done reading before overwrite
    }

    // C/D layout (m89-verified): col = lane&15, row = (lane>>4)*4 + reg
#pragma unroll
    for (int mi = 0; mi < 4; ++mi)
#pragma unroll
        for (int nj = 0; nj < 4; ++nj) {
            int r0 = m0 + wr * 64 + mi * 16 + fq * 4;
            int c  = n0 + wc * 64 + nj * 16 + fr;
#pragma unroll
            for (int r = 0; r < 4; ++r)
                Y[(size_t)(r0 + r) * H1 + c] = acc[mi][nj][r];
        }
}

// ---------------- wave-per-batch SNN scan (v6, unchanged from R7) ----------------
__global__ __launch_bounds__(64) void snn_scan_wave(
    const float* __restrict__ I1ff,   // [B][T][H1]
    const float* __restrict__ wrt,    // [H1][H1]  wrt[i][h] = w_rec[h][i]
    const float* __restrict__ w2t,    // [H1][H2]  w2t[i][g] = w2[g][i]
    const float* __restrict__ w3t,    // [H2][NOUT]
    const float* __restrict__ alpha1, const float* __restrict__ rho1,
    const float* __restrict__ beta_a1,
    const float* __restrict__ alpha2, const float* __restrict__ rho2,
    const float* __restrict__ beta_a2,
    const float* __restrict__ beta_out,
    float* __restrict__ out)          // [B][NOUT]
{
    __shared__ __align__(16) float Ich[2][CH][H1];   // 60 KB

    const int b = blockIdx.x;
    const int lane = threadIdx.x;     // 0..63

    float v1[8], a1[8], s1f[8], al1[8], oml1[8], rh1[8], ba1[8];
#pragma unroll
    for (int j = 0; j < 8; ++j) {
        int h = lane + 64 * j;
        v1[j] = 0.f; a1[j] = 0.f; s1f[j] = 0.f;
        al1[j] = alpha1[h]; oml1[j] = 1.f - al1[j];
        rh1[j] = rho1[h];   ba1[j] = beta_a1[h];
    }
    float v2[4], a2[4], s2f[4], al2[4], oml2[4], rh2[4], ba2[4];
#pragma unroll
    for (int j = 0; j < 4; ++j) {
        int h = lane + 64 * j;
        v2[j] = 0.f; a2[j] = 0.f; s2f[j] = 0.f;
        al2[j] = alpha2[h]; oml2[j] = 1.f - al2[j];
        rh2[j] = rho2[h];   ba2[j] = beta_a2[h];
    }
    float vo0 = 0.f, vo1 = 0.f, vs0 = 0.f, vs1 = 0.f;
    const float bo0 = beta_out[lane];
    const float ombo0 = 1.f - bo0;
    const float bo1 = (lane < NOUT - 64) ? beta_out[64 + lane] : 0.f;
    const float ombo1 = 1.f - bo1;

    unsigned long long M1[8];
#pragma unroll
    for (int j = 0; j < 8; ++j) M1[j] = 0ull;
    bool prev1 = false;

    const float* I1p = I1ff + (size_t)b * T_ * H1;

    auto stage = [&](int c, int bufi) {
        const float* src = I1p + (size_t)c * CH * H1 + lane * 4;
#pragma unroll
        for (int s = 0; s < CH; ++s) {
            LDS_GLOAD16(src + (size_t)s * H1,       &Ich[bufi][s][0]);
            LDS_GLOAD16(src + (size_t)s * H1 + 256, &Ich[bufi][s][256]);
        }
    };

    stage(0, 0);

    for (int c = 0; c < NC; ++c) {
        const int buf = c & 1;
        asm volatile("s_waitcnt vmcnt(0)" ::: "memory");

        float cur[8];
#pragma unroll
        for (int j = 0; j < 8; ++j) cur[j] = Ich[buf][0][lane + 64 * j];

        for (int s = 0; s < CH; ++s) {
            float nxt[8];
            if (s + 1 < CH) {
#pragma unroll
                for (int j = 0; j < 8; ++j) nxt[j] = Ich[buf][s + 1][lane + 64 * j];
            }

            float rec[8] = {0.f,0.f,0.f,0.f,0.f,0.f,0.f,0.f};
            if (prev1) {
#pragma unroll
                for (int w = 0; w < 8; ++w) {
                    unsigned long long bits = M1[w];
                    while (bits) {
                        int p = __builtin_ctzll(bits);
                        bits &= bits - 1;
                        int i = (w << 6) + p;
                        const float* r = wrt + (size_t)i * H1 + lane;
#pragma unroll
                        for (int j = 0; j < 8; ++j) rec[j] += r[64 * j];
                    }
                }
            }

            unsigned m = 0;
#pragma unroll
            for (int j = 0; j < 8; ++j) {
                float I1v = cur[j] + rec[j];
                float v1n = fmaf(al1[j], v1[j], oml1[j] * (I1v - a1[j]));
                bool  sp  = v1n > 1.f;
                v1[j] = sp ? v1n - 1.f : v1n;
                a1[j] = fmaf(rh1[j], a1[j], ba1[j] * s1f[j]);
                s1f[j] = sp ? 1.f : 0.f;
                m |= (sp ? 1u : 0u) << j;
            }

            unsigned long long anyb = __ballot(m != 0);
            float I2[4] = {0.f, 0.f, 0.f, 0.f};
            if (anyb) {
                prev1 = true;
#pragma unroll
                for (int j = 0; j < 8; ++j) M1[j] = __ballot((m >> j) & 1);
#pragma unroll
                for (int w = 0; w < 8; ++w) {
                    unsigned long long bits = M1[w];
                    while (bits) {
                        int p = __builtin_ctzll(bits);
                        bits &= bits - 1;
                        int i = (w << 6) + p;
                        const float* r = w2t + (size_t)i * H2 + lane;
#pragma unroll
                        for (int j = 0; j < 4; ++j) I2[j] += r[64 * j];
                    }
                }
            } else {
                prev1 = false;
            }

            unsigned m2 = 0;
#pragma unroll
            for (int j = 0; j < 4; ++j) {
                float v2n = fmaf(al2[j], v2[j], oml2[j] * (I2[j] - a2[j]));
                bool  sp  = v2n > 1.f;
                v2[j] = sp ? v2n - 1.f : v2n;
                a2[j] = fmaf(rh2[j], a2[j], ba2[j] * s2f[j]);
                s2f[j] = sp ? 1.f : 0.f;
                m2 |= (sp ? 1u : 0u) << j;
            }

            unsigned long long any2 = __ballot(m2 != 0);
            float io0 = 0.f, io1 = 0.f;
            if (any2) {
#pragma unroll
                for (int w = 0; w < 4; ++w) {
                    unsigned long long bits = __ballot((m2 >> w) & 1);
                    while (bits) {
                        int p = __builtin_ctzll(bits);
                        bits &= bits - 1;
                        int i = (w << 6) + p;
                        io0 += w3t[(size_t)i * NOUT + lane];
                        if (lane < NOUT - 64) io1 += w3t[(size_t)i * NOUT + 64 + lane];
                    }
                }
            }
            vo0 = fmaf(bo0, vo0, ombo0 * io0);
            vo1 = fmaf(bo1, vo1, ombo1 * io1);
            vs0 += vo0;
            vs1 += vo1;

#pragma unroll
            for (int j = 0; j < 8; ++j) cur[j] = nxt[j];
        }

        if (c + 1 < NC) stage(c + 1, buf ^ 1);
    }

    out[b * NOUT + lane] = vs0 * (1.f / (float)T_);
    if (lane < NOUT - 64) out[b * NOUT + 64 + lane] = vs1 * (1.f / (float)T_);
}

// ---------------- launch ----------------
extern "C" void kernel_launch(void* const* d_in, const int* in_sizes, int n_in,
                              void* d_out, int out_size, void* d_ws, size_t ws_size,
                              hipStream_t stream) {
    const float* x      = (const float*)d_in[0];   // [B][T][NIN]
    const float* w1     = (const float*)d_in[1];   // [H1][NIN]
    const float* w_rec  = (const float*)d_in[2];   // [H1][H1]
    const float* w2     = (const float*)d_in[3];   // [H2][H1]
    const float* w3     = (const float*)d_in[4];   // [NOUT][H2]
    const float* alpha1 = (const float*)d_in[5];
    const float* rho1   = (const float*)d_in[6];
    const float* beta_a1= (const float*)d_in[7];
    const float* alpha2 = (const float*)d_in[8];
    const float* rho2   = (const float*)d_in[9];
    const float* beta_a2= (const float*)d_in[10];
    const float* beta_out=(const float*)d_in[11];
    float* out = (float*)d_out;

    const int M = B_ * T_;                         // 19200

    size_t off = 0;
    auto take = [&](size_t bytes) {
        void* p = (char*)d_ws + off;
        off += (bytes + 255) & ~(size_t)255;
        return p;
    };
    float* I1ff = (float*)take((size_t)M * H1 * 4);            // 39.3 MB
    float* wrt  = (float*)take((size_t)H1 * H1 * 4);
    float* w2t  = (float*)take((size_t)H1 * H2 * 4);
    float* w3t  = (float*)take((size_t)H2 * NOUT * 4);
    unsigned short* w1b = (unsigned short*)take((size_t)H1 * KP * 2);  // 2.4 MB

    transpose_k<<<(H1 * H1 + 255) / 256, 256, 0, stream>>>(w_rec, wrt, H1, H1);
    transpose_k<<<(H2 * H1 + 255) / 256, 256, 0, stream>>>(w2, w2t, H2, H1);
    transpose_k<<<(NOUT * H2 + 255) / 256, 256, 0, stream>>>(w3, w3t, NOUT, H2);

    // W -> bf16 (tiny); A converts in-GEMM
    int nw = H1 * (KP / 8);
    cvt_pad_bf16<<<(nw + 255) / 256, 256, 0, stream>>>(w1, w1b, H1, NIN, KP);

    dim3 gg(H1 / 128, M / 128);   // (4, 150) = 600 blocks (swizzle assumes 600)
    gemm_bf16_fa<<<gg, 256, 0, stream>>>(x, w1b, I1ff);

    snn_scan_wave<<<B_, 64, 0, stream>>>(I1ff, wrt, w2t, w3t,
                                         alpha1, rho1, beta_a1,
                                         alpha2, rho2, beta_a2,
                                         beta_out, out);
}